// Round 5
// baseline (265.739 us; speedup 1.0000x reference)
//
#include <hip/hip_runtime.h>
#include <hip/hip_bf16.h>

#define NROWS 12288
#define DDIM  128
#define NT    96      // 12288/128 tiles per dimension
#define CHUNK 4       // j-tiles per block
#define NBLK  1200    // sum over bands bi of ceil((96-bi)/4)

typedef __bf16 bf16x8 __attribute__((ext_vector_type(8)));
typedef float  f32x4  __attribute__((ext_vector_type(4)));

__device__ __forceinline__ unsigned short f2bf(float f) {
    union { float f; unsigned u; } a; a.f = f;
    unsigned r = a.u + 0x7fffu + ((a.u >> 16) & 1u);   // RNE to bf16
    return (unsigned short)(r >> 16);
}

__global__ void convert_kernel(const float* __restrict__ x, unsigned short* __restrict__ xb,
                               float* __restrict__ rowsum, unsigned* __restrict__ counter,
                               float* __restrict__ out) {
    int gid = blockIdx.x * 256 + threadIdx.x;
    int i = gid * 4;
    float4 v = *(const float4*)(x + i);
    ushort4 o;
    o.x = f2bf(v.x); o.y = f2bf(v.y); o.z = f2bf(v.z); o.w = f2bf(v.w);
    *(ushort4*)(xb + i) = o;
    if (gid < NROWS) rowsum[gid] = 0.f;
    if (gid == 0) { out[0] = 0.f; *counter = 0u; }
}

// One block per chunk of up-to-4 upper-triangular 128x128 tiles in a row band.
// xb (3 MB bf16) is L2-resident; fragments read directly from global.
// Hot path (full 4-tile strip): manually software-pipelined, depth-2 prefetch,
// NO ds/shfl/atomic ops inside the 16-pass loop (col partials in cpA[16] regs).
// launch_bounds(256,3): ~150 live VGPRs, cap 168. Hard 128 cap => total spill
// (round 3: VGPR=64, 334 MB scratch traffic). Do not tighten.
__global__ __launch_bounds__(256, 3) void gemm_exp_rowsum(
    const unsigned short* __restrict__ xb, float* __restrict__ rowsum,
    unsigned* __restrict__ counter, float* __restrict__ out)
{
    __shared__ float csumS[CHUNK * 128];
    __shared__ float rsum[128];
    __shared__ unsigned doneS;

    const int tid = threadIdx.x;

    // decode blockIdx -> (band bi, chunk start jt0)
    int rem = blockIdx.x, bi = 0;
    for (;;) {
        int nch = (NT - bi + CHUNK - 1) / CHUNK;
        if (rem < nch) break;
        rem -= nch; ++bi;
    }
    const int jt0 = bi + rem * CHUNK;
    const int ntiles = min(CHUNK, NT - jt0);
    const int i0 = bi * 128;

    for (int k = tid; k < CHUNK * 128; k += 256) csumS[k] = 0.f;
    if (tid < 128) rsum[tid] = 0.f;
    __syncthreads();

    const int wave = tid >> 6, lane = tid & 63;
    const int wm = wave >> 1, wn = wave & 1;      // 2x2 waves, 64x64 each
    const int m16 = lane & 15, q = lane >> 4;

    // A fragments straight from global (L2), once per strip: 64 VGPRs.
    bf16x8 af[4][4];
    #pragma unroll
    for (int mi = 0; mi < 4; ++mi) {
        const unsigned short* ap = xb + (size_t)(i0 + wm * 64 + mi * 16 + m16) * DDIM + q * 8;
        #pragma unroll
        for (int ks = 0; ks < 4; ++ks)
            af[mi][ks] = *(const bf16x8*)(ap + ks * 32);
    }

    const float C = 20.609929155556624f;          // (1/0.07)*log2(e) for v_exp_f32
    float rp[4][4];
    #pragma unroll
    for (int mi = 0; mi < 4; ++mi)
        #pragma unroll
        for (int r = 0; r < 4; ++r) rp[mi][r] = 0.f;

    // pass v covers B rows: jt0*128 + (v>>2)*128 + wn*64 + (v&3)*16 + m16
    const unsigned short* bstripe = xb + (size_t)(jt0 * 128 + wn * 64 + m16) * DDIM + q * 8;

    if (ntiles == CHUNK) {
        // ---------- hot path: 16 passes, depth-2 pipelined ----------
        bf16x8 bq[3][4];
        auto loadB = [&](int v, int slot) {
            const unsigned short* bp = bstripe + (size_t)(((v >> 2) * 128 + (v & 3) * 16)) * DDIM;
            #pragma unroll
            for (int ks = 0; ks < 4; ++ks)
                bq[slot][ks] = *(const bf16x8*)(bp + ks * 32);
        };
        loadB(0, 0);
        loadB(1, 1);

        float cpA[16];
        #pragma unroll
        for (int u = 0; u < 16; ++u) {
            if (u + 2 < 16) loadB(u + 2, (u + 2) % 3);

            f32x4 acc[4] = {};
            #pragma unroll
            for (int ks = 0; ks < 4; ++ks)
                #pragma unroll
                for (int mi = 0; mi < 4; ++mi)
                    acc[mi] = __builtin_amdgcn_mfma_f32_16x16x32_bf16(
                        af[mi][ks], bq[u % 3][ks], acc[mi], 0, 0, 0);

            // C/D layout: col(j) = m16, row(i) = q*4 + r  [verified round 1]
            float cp = 0.f;
            #pragma unroll
            for (int mi = 0; mi < 4; ++mi)
                #pragma unroll
                for (int r = 0; r < 4; ++r) {
                    float ev = __builtin_amdgcn_exp2f(acc[mi][r] * C);
                    rp[mi][r] += ev;
                    cp += ev;
                }
            cpA[u] = cp;
        }

        // deferred col-partial reductions (outside the hot loop)
        const bool hasDiag = (jt0 == bi);          // tile t=0 is the diagonal
        #pragma unroll
        for (int u = 0; u < 16; ++u) {
            if (hasDiag && u < 4) continue;        // diagonal: cols == rows, no double count
            float cpv = cpA[u];
            cpv += __shfl_xor(cpv, 16);
            cpv += __shfl_xor(cpv, 32);
            if (q == 0)
                atomicAdd(&csumS[(u >> 2) * 128 + wn * 64 + (u & 3) * 16 + m16], cpv);
        }
    } else {
        // ---------- generic path: partial strips (72/1200 blocks) ----------
        for (int t = 0; t < ntiles; ++t) {
            const bool offd = (jt0 + t != bi);
            #pragma unroll
            for (int p = 0; p < 4; ++p) {
                const unsigned short* bp = bstripe + (size_t)(t * 128 + p * 16) * DDIM;
                bf16x8 bfr[4];
                #pragma unroll
                for (int ks = 0; ks < 4; ++ks)
                    bfr[ks] = *(const bf16x8*)(bp + ks * 32);

                f32x4 acc[4] = {};
                #pragma unroll
                for (int ks = 0; ks < 4; ++ks)
                    #pragma unroll
                    for (int mi = 0; mi < 4; ++mi)
                        acc[mi] = __builtin_amdgcn_mfma_f32_16x16x32_bf16(
                            af[mi][ks], bfr[ks], acc[mi], 0, 0, 0);

                float cp = 0.f;
                #pragma unroll
                for (int mi = 0; mi < 4; ++mi)
                    #pragma unroll
                    for (int r = 0; r < 4; ++r) {
                        float ev = __builtin_amdgcn_exp2f(acc[mi][r] * C);
                        rp[mi][r] += ev;
                        cp += ev;
                    }
                cp += __shfl_xor(cp, 16);
                cp += __shfl_xor(cp, 32);
                if (offd && q == 0)
                    atomicAdd(&csumS[t * 128 + wn * 64 + p * 16 + m16], cp);
            }
        }
    }

    // row reduction: once per block
    #pragma unroll
    for (int mi = 0; mi < 4; ++mi)
        #pragma unroll
        for (int r = 0; r < 4; ++r) {
            float s = rp[mi][r];
            s += __shfl_xor(s, 1);
            s += __shfl_xor(s, 2);
            s += __shfl_xor(s, 4);
            s += __shfl_xor(s, 8);
            if (m16 == 0) atomicAdd(&rsum[wm * 64 + mi * 16 + q * 4 + r], s);
        }
    __syncthreads();

    if (tid < 128) atomicAdd(&rowsum[i0 + tid], rsum[tid]);
    for (int k = tid; k < ntiles * 128; k += 256) {
        float v = csumS[k];
        if (v != 0.f) atomicAdd(&rowsum[jt0 * 128 + k], v);
    }

    // ---- completion counter; last block computes the final loss ----
    // __syncthreads drains vmcnt => this block's rowsum atomics reached the
    // device-coherent point before the counter bump.
    __syncthreads();
    if (tid == 0) {
        __threadfence();
        doneS = atomicAdd(counter, 1u);
    }
    __syncthreads();
    if (doneS == NBLK - 1) {
        float a = 0.f;
        for (int i = tid; i < NROWS; i += 256)
            a += __logf(atomicAdd(&rowsum[i], 0.0f));   // coherent read (L2 RMW)
        #pragma unroll
        for (int off = 1; off < 64; off <<= 1)
            a += __shfl_xor(a, off);
        if (lane == 0) rsum[wave] = a;
        __syncthreads();
        if (tid == 0)
            out[0] = (rsum[0] + rsum[1] + rsum[2] + rsum[3]) * (1.0f / (float)NROWS);
    }
}

extern "C" void kernel_launch(void* const* d_in, const int* in_sizes, int n_in,
                              void* d_out, int out_size, void* d_ws, size_t ws_size,
                              hipStream_t stream) {
    const float* x = (const float*)d_in[0];
    float* out = (float*)d_out;

    float* rowsum = (float*)d_ws;                                   // 48 KB
    unsigned* counter = (unsigned*)((char*)d_ws + NROWS * sizeof(float));
    unsigned short* xb = (unsigned short*)((char*)d_ws + NROWS * sizeof(float) + 256); // 3 MB bf16

    convert_kernel<<<dim3((NROWS * DDIM) / (4 * 256)), dim3(256), 0, stream>>>(x, xb, rowsum, counter, out);
    gemm_exp_rowsum<<<dim3(NBLK), dim3(256), 0, stream>>>(xb, rowsum, counter, out);
}

// Round 6
// 126.760 us; speedup vs baseline: 2.0964x; 2.0964x over previous
//
#include <hip/hip_runtime.h>
#include <hip/hip_bf16.h>

#define NROWS 12288
#define DDIM  128
#define NT    96      // 12288/128 tiles per dimension
#define CHUNK 4       // j-tiles per block
#define NBLK  1200    // sum over bands bi of ceil((96-bi)/4)

typedef __bf16 bf16x8 __attribute__((ext_vector_type(8)));
typedef float  f32x4  __attribute__((ext_vector_type(4)));

// async global->LDS, 16B per lane; LDS dst is wave-uniform base + lane*16
#define GLD_LDS(g, l) __builtin_amdgcn_global_load_lds(                      \
    (const __attribute__((address_space(1))) void*)(g),                      \
    (__attribute__((address_space(3))) void*)(l), 16, 0, 0)

__device__ __forceinline__ unsigned short f2bf(float f) {
    union { float f; unsigned u; } a; a.f = f;
    unsigned r = a.u + 0x7fffu + ((a.u >> 16) & 1u);   // RNE to bf16
    return (unsigned short)(r >> 16);
}

__global__ void convert_kernel(const float* __restrict__ x, unsigned short* __restrict__ xb,
                               float* __restrict__ rowsum, unsigned* __restrict__ counter,
                               float* __restrict__ out) {
    int gid = blockIdx.x * 256 + threadIdx.x;
    int i = gid * 4;
    float4 v = *(const float4*)(x + i);
    ushort4 o;
    o.x = f2bf(v.x); o.y = f2bf(v.y); o.z = f2bf(v.z); o.w = f2bf(v.w);
    *(ushort4*)(xb + i) = o;
    if (gid < NROWS) rowsum[gid] = 0.f;
    if (gid == 0) { out[0] = 0.f; *counter = 0u; }
}

// Stage one 128x128 bf16 tile into LDS, XOR-swizzled:
// LDS slot (row, s) holds global 16B-chunk (s ^ (row&7)) of that row.
__device__ __forceinline__ void stage_tile(const unsigned short* __restrict__ xb,
                                           int row0, unsigned short* lds,
                                           int wave, int lane) {
    #pragma unroll
    for (int it = 0; it < 8; ++it) {
        int rbase = wave * 32 + it * 4;               // wave-uniform
        int r = rbase + (lane >> 4);
        int chunk = (lane & 15) ^ (r & 7);
        GLD_LDS(xb + (size_t)(row0 + r) * DDIM + chunk * 8, lds + rbase * DDIM);
    }
}

// One block per chunk of up-to-4 upper-triangular 128x128 tiles in a row band.
// Double-buffered LDS B-tiles: DMA for tile t+1 issued BEFORE computing tile t,
// single barrier per tile => the vmcnt(0) drain at the barrier lands ~1.5k cyc
// after DMA issue (hidden). A-fragments VGPR-resident for the strip (staged
// once through Bs0, which is then recycled as a B buffer).
// ANTI-SPILL DISCIPLINE (rounds 3&5 post-mortems): launch_bounds(256,2) only
// (cap 256 VGPR — a 128 cap or any dynamically-indexed register array causes
// total scratch spill: VGPR=64-84 + 300+ MB scratch traffic). All register
// arrays constant-indexed under full unrolls; buffer swap via scalar pointers.
__global__ __launch_bounds__(256, 2) void gemm_exp_rowsum(
    const unsigned short* __restrict__ xb, float* __restrict__ rowsum,
    unsigned* __restrict__ counter, float* __restrict__ out)
{
    __shared__ __align__(16) unsigned short Bs0[128 * DDIM];   // 32 KB
    __shared__ __align__(16) unsigned short Bs1[128 * DDIM];   // 32 KB
    __shared__ float csumS[CHUNK * 128];
    __shared__ float rsum[128];
    __shared__ unsigned doneS;

    const int tid = threadIdx.x;

    // decode blockIdx -> (band bi, chunk start jt0)
    int rem = blockIdx.x, bi = 0;
    for (;;) {
        int nch = (NT - bi + CHUNK - 1) / CHUNK;
        if (rem < nch) break;
        rem -= nch; ++bi;
    }
    const int jt0 = bi + rem * CHUNK;
    const int ntiles = min(CHUNK, NT - jt0);
    const int i0 = bi * 128;

    for (int k = tid; k < CHUNK * 128; k += 256) csumS[k] = 0.f;
    if (tid < 128) rsum[tid] = 0.f;

    const int wave = tid >> 6, lane = tid & 63;
    const int wm = wave >> 1, wn = wave & 1;      // 2x2 waves, 64x64 each
    const int m16 = lane & 15, q = lane >> 4;

    // ---- stage A through Bs0, pull fragments into VGPRs (once per strip) ----
    stage_tile(xb, i0, Bs0, wave, lane);
    __syncthreads();                               // A DMA drained (+ LDS zero-init visible)

    bf16x8 af[4][4];                               // [mi][ks] — 64 VGPRs, strip-resident
    #pragma unroll
    for (int mi = 0; mi < 4; ++mi) {
        int r = wm * 64 + mi * 16 + m16;
        #pragma unroll
        for (int ks = 0; ks < 4; ++ks)
            af[mi][ks] = *(const bf16x8*)(&Bs0[r * DDIM + (((ks * 4 + q) ^ (r & 7)) * 8)]);
    }
    stage_tile(xb, jt0 * 128, Bs1, wave, lane);    // B_0 -> Bs1, overlaps af ds_reads
    __syncthreads();                               // af reads done + B_0 DMA drained

    const float C = 20.609929155556624f;           // (1/0.07)*log2(e) for v_exp_f32
    float rp[4][4];                                // row partials, whole strip
    #pragma unroll
    for (int mi = 0; mi < 4; ++mi)
        #pragma unroll
        for (int r = 0; r < 4; ++r) rp[mi][r] = 0.f;

    const unsigned short* cur = Bs1;               // tile t in buf[(t+1)&1]
    unsigned short* nxt = Bs0;

    for (int t = 0; t < ntiles; ++t) {
        // prefetch B_{t+1} into the idle buffer FIRST — DMA flies during compute
        if (t + 1 < ntiles) stage_tile(xb, (jt0 + t + 1) * 128, nxt, wave, lane);

        f32x4 acc[4][4] = {};
        #pragma unroll
        for (int ks = 0; ks < 4; ++ks) {
            bf16x8 bfr[4];
            #pragma unroll
            for (int ni = 0; ni < 4; ++ni) {
                int r = wn * 64 + ni * 16 + m16;
                bfr[ni] = *(const bf16x8*)(&cur[r * DDIM + (((ks * 4 + q) ^ (r & 7)) * 8)]);
            }
            #pragma unroll
            for (int mi = 0; mi < 4; ++mi)
                #pragma unroll
                for (int ni = 0; ni < 4; ++ni)
                    acc[mi][ni] = __builtin_amdgcn_mfma_f32_16x16x32_bf16(
                        af[mi][ks], bfr[ni], acc[mi][ni], 0, 0, 0);
        }

        // C/D layout: col(j) = m16, row(i) = q*4 + r  [verified round 1]
        float cp[4] = {0.f, 0.f, 0.f, 0.f};
        #pragma unroll
        for (int mi = 0; mi < 4; ++mi)
            #pragma unroll
            for (int ni = 0; ni < 4; ++ni)
                #pragma unroll
                for (int r = 0; r < 4; ++r) {
                    float ev = __builtin_amdgcn_exp2f(acc[mi][ni][r] * C);
                    rp[mi][r] += ev;
                    cp[ni] += ev;
                }

        if (jt0 + t != bi) {                       // diagonal: cols==rows, no double count
            #pragma unroll
            for (int ni = 0; ni < 4; ++ni) {
                float s = cp[ni];
                s += __shfl_xor(s, 16);
                s += __shfl_xor(s, 32);
                if (q == 0) atomicAdd(&csumS[t * 128 + wn * 64 + ni * 16 + m16], s);
            }
        }

        __syncthreads();                           // cur reads done + nxt DMA drained
        const unsigned short* tswap = cur; cur = nxt; nxt = (unsigned short*)tswap;
    }

    // row reduction: once per block
    #pragma unroll
    for (int mi = 0; mi < 4; ++mi)
        #pragma unroll
        for (int r = 0; r < 4; ++r) {
            float s = rp[mi][r];
            s += __shfl_xor(s, 1);
            s += __shfl_xor(s, 2);
            s += __shfl_xor(s, 4);
            s += __shfl_xor(s, 8);
            if (m16 == 0) atomicAdd(&rsum[wm * 64 + mi * 16 + q * 4 + r], s);
        }
    __syncthreads();

    if (tid < 128) atomicAdd(&rowsum[i0 + tid], rsum[tid]);
    for (int k = tid; k < ntiles * 128; k += 256) {
        float v = csumS[k];
        if (v != 0.f) atomicAdd(&rowsum[jt0 * 128 + k], v);
    }

    // ---- completion counter; last block computes the final loss (R5-proven) ----
    __syncthreads();
    if (tid == 0) {
        __threadfence();
        doneS = atomicAdd(counter, 1u);
    }
    __syncthreads();
    if (doneS == NBLK - 1) {
        float a = 0.f;
        for (int i = tid; i < NROWS; i += 256)
            a += __logf(atomicAdd(&rowsum[i], 0.0f));   // device-coherent read (L2 RMW)
        #pragma unroll
        for (int off = 1; off < 64; off <<= 1)
            a += __shfl_xor(a, off);
        if (lane == 0) rsum[wave] = a;
        __syncthreads();
        if (tid == 0)
            out[0] = (rsum[0] + rsum[1] + rsum[2] + rsum[3]) * (1.0f / (float)NROWS);
    }
}

extern "C" void kernel_launch(void* const* d_in, const int* in_sizes, int n_in,
                              void* d_out, int out_size, void* d_ws, size_t ws_size,
                              hipStream_t stream) {
    const float* x = (const float*)d_in[0];
    float* out = (float*)d_out;

    float* rowsum = (float*)d_ws;                                   // 48 KB
    unsigned* counter = (unsigned*)((char*)d_ws + NROWS * sizeof(float));
    unsigned short* xb = (unsigned short*)((char*)d_ws + NROWS * sizeof(float) + 256); // 3 MB bf16

    convert_kernel<<<dim3((NROWS * DDIM) / (4 * 256)), dim3(256), 0, stream>>>(x, xb, rowsum, counter, out);
    gemm_exp_rowsum<<<dim3(NBLK), dim3(256), 0, stream>>>(xb, rowsum, counter, out);
}

// Round 7
// 125.034 us; speedup vs baseline: 2.1253x; 1.0138x over previous
//
#include <hip/hip_runtime.h>
#include <hip/hip_bf16.h>

#define NROWS 12288
#define DDIM  128
#define NT    96      // 12288/128 tiles per dimension
#define CHUNK 4       // j-tiles per block
#define NBLK  1200    // sum over bands bi of ceil((96-bi)/4)

typedef __bf16 bf16x8 __attribute__((ext_vector_type(8)));
typedef float  f32x4  __attribute__((ext_vector_type(4)));

// async global->LDS, 16B per lane; LDS dst is wave-uniform base + lane*16
#define GLD_LDS(g, l) __builtin_amdgcn_global_load_lds(                      \
    (const __attribute__((address_space(1))) void*)(g),                      \
    (__attribute__((address_space(3))) void*)(l), 16, 0, 0)

__device__ __forceinline__ unsigned short f2bf(float f) {
    union { float f; unsigned u; } a; a.f = f;
    unsigned r = a.u + 0x7fffu + ((a.u >> 16) & 1u);   // RNE to bf16
    return (unsigned short)(r >> 16);
}

__global__ void convert_kernel(const float* __restrict__ x, unsigned short* __restrict__ xb,
                               float* __restrict__ rowsum, unsigned* __restrict__ counter,
                               float* __restrict__ out) {
    int gid = blockIdx.x * 256 + threadIdx.x;
    int i = gid * 4;
    float4 v = *(const float4*)(x + i);
    ushort4 o;
    o.x = f2bf(v.x); o.y = f2bf(v.y); o.z = f2bf(v.z); o.w = f2bf(v.w);
    *(ushort4*)(xb + i) = o;
    if (gid < NROWS) rowsum[gid] = 0.f;
    if (gid == 0) { out[0] = 0.f; *counter = 0u; }
}

// Stage one 128x128 bf16 tile into LDS, XOR-swizzled:
// LDS slot (row, s) holds global 16B-chunk (s ^ (row&7)) of that row.
__device__ __forceinline__ void stage_tile(const unsigned short* __restrict__ xb,
                                           int row0, unsigned short* lds,
                                           int wave, int lane) {
    #pragma unroll
    for (int it = 0; it < 8; ++it) {
        int rbase = wave * 32 + it * 4;               // wave-uniform
        int r = rbase + (lane >> 4);
        int chunk = (lane & 15) ^ (r & 7);
        GLD_LDS(xb + (size_t)(row0 + r) * DDIM + chunk * 8, lds + rbase * DDIM);
    }
}

// One block per chunk of up-to-4 upper-triangular 128x128 tiles in a row band.
// OCCUPANCY-FIRST design (R2..R6 lesson: intra-wave pipelining tricks all lost;
// 2 blocks/CU was the limiter): each wave computes a 32x128 strip (rows
// 32w..32w+31, ALL cols) => per-wave regs ~100 (af 32 + bfr 16 + acc 8 + rp 8),
// single fixed-address 32KB B-buffer + 2.5KB reductions = ~35KB LDS
// => 4 blocks/CU, 16 waves/CU, VGPR cap 128 via launch_bounds(256,4).
// ANTI-SPILL DISCIPLINE (R3/R5): all register arrays constant-indexed; no
// pointer-swapped LDS buffers (R6: runtime LDS bases serialize DMA vs ds_read);
// ni-loop unroll 2 only (full unroll could hoist 8x bfr = 128 regs).
__global__ __launch_bounds__(256, 4) void gemm_exp_rowsum(
    const unsigned short* __restrict__ xb, float* __restrict__ rowsum,
    unsigned* __restrict__ counter, float* __restrict__ out)
{
    __shared__ __align__(16) unsigned short Bs[128 * DDIM];   // 32 KB
    __shared__ float csumS[CHUNK * 128];
    __shared__ float rsum[128];
    __shared__ unsigned doneS;

    const int tid = threadIdx.x;

    // decode blockIdx -> (band bi, chunk start jt0)
    int rem = blockIdx.x, bi = 0;
    for (;;) {
        int nch = (NT - bi + CHUNK - 1) / CHUNK;
        if (rem < nch) break;
        rem -= nch; ++bi;
    }
    const int jt0 = bi + rem * CHUNK;
    const int ntiles = min(CHUNK, NT - jt0);
    const int i0 = bi * 128;

    for (int k = tid; k < CHUNK * 128; k += 256) csumS[k] = 0.f;
    if (tid < 128) rsum[tid] = 0.f;

    const int wave = tid >> 6, lane = tid & 63;
    const int m16 = lane & 15, q = lane >> 4;

    // ---- stage A through Bs, pull this wave's 32-row strip into VGPRs ----
    stage_tile(xb, i0, Bs, wave, lane);
    __syncthreads();                               // A DMA drained; LDS zero-init visible

    bf16x8 af[2][4];                               // rows 32*wave + mi*16 + m16; 32 VGPRs
    #pragma unroll
    for (int mi = 0; mi < 2; ++mi) {
        int r = wave * 32 + mi * 16 + m16;
        #pragma unroll
        for (int ks = 0; ks < 4; ++ks)
            af[mi][ks] = *(const bf16x8*)(&Bs[r * DDIM + (((ks * 4 + q) ^ (r & 7)) * 8)]);
    }

    const float C = 20.609929155556624f;           // (1/0.07)*log2(e) for v_exp_f32
    float rp[2][4];                                // row partials, whole strip
    #pragma unroll
    for (int mi = 0; mi < 2; ++mi)
        #pragma unroll
        for (int r = 0; r < 4; ++r) rp[mi][r] = 0.f;

    for (int t = 0; t < ntiles; ++t) {
        const int jt = jt0 + t;
        const bool offd = (jt != bi);
        __syncthreads();                           // af reads done (t=0) / prev tile reads done
        stage_tile(xb, jt * 128, Bs, wave, lane);
        __syncthreads();                           // B_t DMA drained

        #pragma unroll 2
        for (int ni = 0; ni < 8; ++ni) {
            // B fragment rows (= tile cols) ni*16 + m16
            int br = ni * 16 + m16;
            bf16x8 bfr[4];
            #pragma unroll
            for (int ks = 0; ks < 4; ++ks)
                bfr[ks] = *(const bf16x8*)(&Bs[br * DDIM + (((ks * 4 + q) ^ (br & 7)) * 8)]);

            f32x4 acc[2] = {};
            #pragma unroll
            for (int ks = 0; ks < 4; ++ks)
                #pragma unroll
                for (int mi = 0; mi < 2; ++mi)
                    acc[mi] = __builtin_amdgcn_mfma_f32_16x16x32_bf16(
                        af[mi][ks], bfr[ks], acc[mi], 0, 0, 0);

            // C/D layout: col(j)=ni*16+m16, row(i)=32w+mi*16+q*4+r  [verified R1]
            float cp = 0.f;
            #pragma unroll
            for (int mi = 0; mi < 2; ++mi)
                #pragma unroll
                for (int r = 0; r < 4; ++r) {
                    float ev = __builtin_amdgcn_exp2f(acc[mi][r] * C);
                    rp[mi][r] += ev;
                    cp += ev;
                }
            // col partial: this wave's 32-row band for col ni*16+m16
            cp += __shfl_xor(cp, 16);
            cp += __shfl_xor(cp, 32);
            if (offd && q == 0)
                atomicAdd(&csumS[t * 128 + ni * 16 + m16], cp);
        }
    }

    // row reduction: once per block
    #pragma unroll
    for (int mi = 0; mi < 2; ++mi)
        #pragma unroll
        for (int r = 0; r < 4; ++r) {
            float s = rp[mi][r];
            s += __shfl_xor(s, 1);
            s += __shfl_xor(s, 2);
            s += __shfl_xor(s, 4);
            s += __shfl_xor(s, 8);
            if (m16 == 0) atomicAdd(&rsum[wave * 32 + mi * 16 + q * 4 + r], s);
        }
    __syncthreads();

    if (tid < 128) atomicAdd(&rowsum[i0 + tid], rsum[tid]);
    for (int k = tid; k < ntiles * 128; k += 256) {
        float v = csumS[k];
        if (v != 0.f) atomicAdd(&rowsum[jt0 * 128 + k], v);
    }

    // ---- completion counter; last block computes the final loss (R5/R6-proven) ----
    __syncthreads();
    if (tid == 0) {
        __threadfence();
        doneS = atomicAdd(counter, 1u);
    }
    __syncthreads();
    if (doneS == NBLK - 1) {
        float a = 0.f;
        for (int i = tid; i < NROWS; i += 1024) {     // 12 iters x 4 independent reads
            float v0 = atomicAdd(&rowsum[i], 0.0f);
            float v1 = atomicAdd(&rowsum[i + 256], 0.0f);
            float v2 = atomicAdd(&rowsum[i + 512], 0.0f);
            float v3 = atomicAdd(&rowsum[i + 768], 0.0f);
            a += __logf(v0) + __logf(v1) + __logf(v2) + __logf(v3);
        }
        #pragma unroll
        for (int off = 1; off < 64; off <<= 1)
            a += __shfl_xor(a, off);
        if (lane == 0) rsum[wave] = a;
        __syncthreads();
        if (tid == 0)
            out[0] = (rsum[0] + rsum[1] + rsum[2] + rsum[3]) * (1.0f / (float)NROWS);
    }
}

extern "C" void kernel_launch(void* const* d_in, const int* in_sizes, int n_in,
                              void* d_out, int out_size, void* d_ws, size_t ws_size,
                              hipStream_t stream) {
    const float* x = (const float*)d_in[0];
    float* out = (float*)d_out;

    float* rowsum = (float*)d_ws;                                   // 48 KB
    unsigned* counter = (unsigned*)((char*)d_ws + NROWS * sizeof(float));
    unsigned short* xb = (unsigned short*)((char*)d_ws + NROWS * sizeof(float) + 256); // 3 MB bf16

    convert_kernel<<<dim3((NROWS * DDIM) / (4 * 256)), dim3(256), 0, stream>>>(x, xb, rowsum, counter, out);
    gemm_exp_rowsum<<<dim3(NBLK), dim3(256), 0, stream>>>(xb, rowsum, counter, out);
}